// Round 2
// baseline (3241.176 us; speedup 1.0000x reference)
//
#include <hip/hip_runtime.h>
#include <hip/hip_bf16.h>
#include <type_traits>

// ViT-Base/16 forward. Round 5: T2 LDS XOR-swizzle in bgemm (pre-swizzled
// global source + swizzled fragment reads; global_load_lds dest stays linear
// per rule #21). Kills the 8-way bank conflict on every ds_read_b128.

#define BV   32
#define DIM  768
#define NHD  12
#define DH   64
#define NSEQ 197
#define NPAT 196
#define MLPD 3072
#define NCLS 1000
#define NLAYER 12

typedef __hip_bfloat16 bf16;
typedef __attribute__((ext_vector_type(8))) short s8v;    // 8 bf16 (4 VGPRs)
typedef __attribute__((ext_vector_type(4))) float f32x4;  // MFMA acc

#define GLDS16(gp, lp) __builtin_amdgcn_global_load_lds( \
    (const __attribute__((address_space(1))) void*)(gp), \
    (__attribute__((address_space(3))) void*)(lp), 16, 0, 0)

__device__ __forceinline__ short f2bf(float v) {
    return (short)__bfloat16_as_ushort(__float2bfloat16(v));
}

// ------------------------------------------------------------- MFMA GEMM ----
// C[M,N] = epilogue(A @ B^T + bias), A: [M,K] bf16 (lda), B: [N,K] bf16 (ldb),
// both K-contiguous. TO = float or bf16. ACT=1 -> exact GELU. RESID (float
// only): C += result. K % 32 == 0. Tile 128x128, BK=32, 4 waves (2x2).
// K-loop: 3-deep LDS pipeline (counted vmcnt) + XOR-swizzled tiles.
//
// Swizzle: logical LDS tile is [row][4 slots of 16B]; chunk s of row r is
// stored at slot s ^ ((r>>1)&3). Write side: global_load_lds writes lane i
// linearly at row (c*16 + i>>2), slot (i&3), so lane i LOADS global chunk
// (i&3) ^ (((i>>2)>>1)&3) — same 64B row window, coalescing unchanged.
// Read side: fragment (colr, quad) reads slot quad ^ ((colr>>1)&3); the
// i*16-row step doesn't change the XOR, so it folds into the base pointer.
// Result: 64 lanes uniform over 16B-superbanks (2-way = free, m136).
template<int ACT, bool RESID, typename TO>
__global__ __launch_bounds__(256)
void bgemm(const bf16* __restrict__ A, const bf16* __restrict__ B,
           const float* __restrict__ bias, TO* __restrict__ C,
           int M, int N, int K, int lda, int ldb, int ldc)
{
    __shared__ short As[24576];   // 3 bufs x (A 4096 + B 4096) shorts = 48 KB

    // XCD-aware swizzle: balanced bijection, XCD x owns a contiguous
    // row-major tile range (shares A panels, streams B).
    int nbx = gridDim.x;
    int nb  = nbx * gridDim.y;
    int bid = blockIdx.y * nbx + blockIdx.x;
    {
        int per = nb >> 3, rem = nb & 7;
        int x = bid & 7, loc = bid >> 3;
        bid = x * per + (x < rem ? x : rem) + loc;
    }
    const int m0 = (bid / nbx) * 128;
    const int n0 = (bid % nbx) * 128;

    const int tid  = threadIdx.x;
    const int wave = tid >> 6;
    const int lane = tid & 63;

    const int c0 = wave * 2, c1 = c0 + 1;
    const int rsub = lane >> 2;
    // T2: pre-swizzled source column (inverse perm == forward perm, involution)
    const int kp8  = (((lane & 3) ^ ((rsub >> 1) & 3)) * 8);

    int ra0 = m0 + c0 * 16 + rsub; if (ra0 > M - 1) ra0 = M - 1;
    int ra1 = m0 + c1 * 16 + rsub; if (ra1 > M - 1) ra1 = M - 1;
    int rb0 = n0 + c0 * 16 + rsub; if (rb0 > N - 1) rb0 = N - 1;
    int rb1 = n0 + c1 * 16 + rsub; if (rb1 > N - 1) rb1 = N - 1;

    const bf16* pa0 = A + (long)ra0 * lda + kp8;
    const bf16* pa1 = A + (long)ra1 * lda + kp8;
    const bf16* pb0 = B + (long)rb0 * ldb + kp8;
    const bf16* pb1 = B + (long)rb1 * ldb + kp8;

    const int wm = wave >> 1, wn = wave & 1;
    const int colr = lane & 15;
    const int quad = lane >> 4;

    f32x4 acc[4][4];
    #pragma unroll
    for (int i = 0; i < 4; ++i)
        #pragma unroll
        for (int j = 0; j < 4; ++j)
            acc[i][j] = (f32x4){0.f, 0.f, 0.f, 0.f};

    // T2: swizzled fragment-read slot
    const int sq = quad ^ ((colr >> 1) & 3);
    const short* AsP = &As[(wm * 64 + colr) * 32 + sq * 8];
    const short* BsP = &As[4096 + (wn * 64 + colr) * 32 + sq * 8];

#define STAGE(bufi) do {                              \
        int _o = (bufi) * 8192;                       \
        GLDS16(pa0, &As[_o + c0 * 512]);              \
        GLDS16(pa1, &As[_o + c1 * 512]);              \
        GLDS16(pb0, &As[_o + 4096 + c0 * 512]);       \
        GLDS16(pb1, &As[_o + 4096 + c1 * 512]);       \
        pa0 += 32; pa1 += 32; pb0 += 32; pb1 += 32;   \
    } while (0)

    const int nt = K >> 5;        // K / 32, always >= 24 here
    STAGE(0);
    STAGE(1);
    int cur = 0, nxt = 2;

    for (int t = 0; t < nt; ++t) {
        if (t + 2 < nt) {
            STAGE(nxt);
            nxt = (nxt == 2) ? 0 : nxt + 1;
            // 8 newer loads (tiles t+1, t+2) stay in flight; tile t is done.
            asm volatile("s_waitcnt vmcnt(8)" ::: "memory");
        } else if (t + 1 < nt) {
            asm volatile("s_waitcnt vmcnt(4)" ::: "memory");
        } else {
            asm volatile("s_waitcnt vmcnt(0)" ::: "memory");
        }
        __builtin_amdgcn_s_barrier();            // tile t visible to all waves
        asm volatile("" ::: "memory");

        const short* Ab = AsP + cur * 8192;
        const short* Bb = BsP + cur * 8192;
        s8v a[4], b[4];
        #pragma unroll
        for (int i = 0; i < 4; ++i) a[i] = *(const s8v*)(Ab + i * 512);
        #pragma unroll
        for (int j = 0; j < 4; ++j) b[j] = *(const s8v*)(Bb + j * 512);
        #pragma unroll
        for (int i = 0; i < 4; ++i)
            #pragma unroll
            for (int j = 0; j < 4; ++j)
                acc[i][j] = __builtin_amdgcn_mfma_f32_16x16x32_bf16(
                    a[i], b[j], acc[i][j], 0, 0, 0);

        cur = (cur == 2) ? 0 : cur + 1;
        asm volatile("" ::: "memory");
        __builtin_amdgcn_s_barrier();            // buf[cur] free to overwrite
        asm volatile("" ::: "memory");
    }
#undef STAGE

    // ---- epilogue: per-wave LDS transpose -> vectorized stores ----
    // C/D layout: col = lane&15, row = quad*4 + reg   [m89-verified]
    float* ep = ((float*)As) + wave * 1024;   // 16x64 fp32 per wave (16 KB tot)
    const int lrow = lane >> 2;
    const int lc4  = (lane & 3) * 16;

    #pragma unroll
    for (int i = 0; i < 4; ++i) {
        #pragma unroll
        for (int j = 0; j < 4; ++j)
            #pragma unroll
            for (int r = 0; r < 4; ++r)
                ep[(quad * 4 + r) * 64 + j * 16 + colr] = acc[i][j][r];
        __syncthreads();

        int gm = m0 + wm * 64 + i * 16 + lrow;
        int gn = n0 + wn * 64 + lc4;
        if (gm < M) {
            float vals[16];
            #pragma unroll
            for (int c = 0; c < 16; ++c) vals[c] = ep[lrow * 64 + lc4 + c];

            if (gn + 16 <= N) {
                if (bias) {
                    #pragma unroll
                    for (int c = 0; c < 16; ++c) vals[c] += bias[gn + c];
                }
                if (ACT == 1) {
                    #pragma unroll
                    for (int c = 0; c < 16; ++c)
                        vals[c] = 0.5f * vals[c] *
                                  (1.0f + erff(vals[c] * 0.70710678118654752f));
                }
                if constexpr (std::is_same<TO, float>::value) {
                    float* Cp = (float*)C + (long)gm * ldc + gn;
                    if constexpr (RESID) {
                        #pragma unroll
                        for (int c4 = 0; c4 < 4; ++c4) {
                            f32x4 old = *(const f32x4*)&Cp[c4 * 4];
                            #pragma unroll
                            for (int e = 0; e < 4; ++e) vals[c4 * 4 + e] += old[e];
                        }
                    }
                    #pragma unroll
                    for (int c4 = 0; c4 < 4; ++c4) {
                        f32x4 v;
                        #pragma unroll
                        for (int e = 0; e < 4; ++e) v[e] = vals[c4 * 4 + e];
                        *(f32x4*)&Cp[c4 * 4] = v;
                    }
                } else {
                    short* Cp = (short*)C + (long)gm * ldc + gn;
                    s8v v0, v1;
                    #pragma unroll
                    for (int e = 0; e < 8; ++e) { v0[e] = f2bf(vals[e]); v1[e] = f2bf(vals[8 + e]); }
                    *(s8v*)&Cp[0] = v0;
                    *(s8v*)&Cp[8] = v1;
                }
            } else {
                // partial-N fallback (head GEMM, N=1000)
                #pragma unroll
                for (int c = 0; c < 16; ++c) {
                    int g = gn + c;
                    if (g >= N) continue;
                    float v = vals[c];
                    if (bias) v += bias[g];
                    if (ACT == 1) v = 0.5f * v * (1.0f + erff(v * 0.70710678118654752f));
                    long idx = (long)gm * ldc + g;
                    if constexpr (RESID) v += ((const float*)C)[idx];
                    if constexpr (std::is_same<TO, float>::value) C[idx] = v;
                    else C[idx] = __float2bfloat16(v);
                }
            }
        }
        __syncthreads();
    }
}

// --------------------------------------------------- fused flash attention --
// One WG (4 waves) per (b, h, 64-row Q tile). qkv: [B*197][2304] bf16
// (q|k|v, head-contig 64). O: [B*197][768] bf16.
__global__ __launch_bounds__(256)
void attn_kernel(const bf16* __restrict__ qkv, bf16* __restrict__ O)
{
    __shared__ short Qs[64 * 72];    // +8 pad: kills 16-way frag-read conflicts
    __shared__ short Ks[224 * 72];   // P (64x224) overlays after S-phase
    __shared__ short Vt[64 * 224];   // V transposed [d][seq]

    const int tid  = threadIdx.x;
    const int wave = tid >> 6;
    const int lane = tid & 63;
    const int q0 = blockIdx.x * 64;
    const int b  = blockIdx.y / NHD;
    const int h  = blockIdx.y % NHD;
    const bf16* base = qkv + (long)b * NSEQ * (3 * DIM);

    // ---- stage Q (64x64), K (224x64, clamped), Vt (64x224, clamped) ----
    #pragma unroll
    for (int p = 0; p < 2; ++p) {
        int idx = p * 2048 + tid * 8;
        int row = idx >> 6, col = idx & 63;
        int gr = q0 + row; if (gr > NSEQ - 1) gr = NSEQ - 1;
        *(s8v*)&Qs[row * 72 + col] =
            *(const s8v*)&base[(long)gr * (3 * DIM) + h * DH + col];
    }
    #pragma unroll
    for (int p = 0; p < 7; ++p) {
        int idx = p * 2048 + tid * 8;
        int row = idx >> 6, col = idx & 63;
        int gr = row; if (gr > NSEQ - 1) gr = NSEQ - 1;
        *(s8v*)&Ks[row * 72 + col] =
            *(const s8v*)&base[(long)gr * (3 * DIM) + DIM + h * DH + col];
    }
    {
        int seqL = tid & 31, dc = tid >> 5;   // dc 0..7
        #pragma unroll
        for (int st = 0; st < 7; ++st) {
            int seq = st * 32 + seqL;
            int gr = seq; if (gr > NSEQ - 1) gr = NSEQ - 1;
            s8v v = *(const s8v*)&base[(long)gr * (3 * DIM) + 2 * DIM + h * DH + dc * 8];
            #pragma unroll
            for (int i = 0; i < 8; ++i)
                Vt[(dc * 8 + i) * 224 + seq] = v[i];
        }
    }
    __syncthreads();

    const int colr = lane & 15;
    const int quad = lane >> 4;

    // ---- S = Q @ K^T : each wave = 16 rows x 224 cols, K=64 ----
    f32x4 s[14];
    #pragma unroll
    for (int j = 0; j < 14; ++j) s[j] = (f32x4){0.f, 0.f, 0.f, 0.f};
    #pragma unroll
    for (int kk = 0; kk < 2; ++kk) {
        s8v a = *(const s8v*)&Qs[(wave * 16 + colr) * 72 + quad * 8 + kk * 32];
        #pragma unroll
        for (int j = 0; j < 14; ++j) {
            s8v bf = *(const s8v*)&Ks[(j * 16 + colr) * 72 + quad * 8 + kk * 32];
            s[j] = __builtin_amdgcn_mfma_f32_16x16x32_bf16(a, bf, s[j], 0, 0, 0);
        }
    }

    // ---- softmax (rows: quad*4+r within wave slice; col: j*16+colr) ----
    float mx[4] = {-1e30f, -1e30f, -1e30f, -1e30f};
    #pragma unroll
    for (int j = 0; j < 14; ++j) {
        int c = j * 16 + colr;
        #pragma unroll
        for (int r = 0; r < 4; ++r) {
            s[j][r] *= 0.125f;
            if (c < NSEQ) mx[r] = fmaxf(mx[r], s[j][r]);
        }
    }
    #pragma unroll
    for (int off = 1; off <= 8; off <<= 1)
        #pragma unroll
        for (int r = 0; r < 4; ++r)
            mx[r] = fmaxf(mx[r], __shfl_xor(mx[r], off));

    float sum[4] = {0.f, 0.f, 0.f, 0.f};
    #pragma unroll
    for (int j = 0; j < 14; ++j) {
        int c = j * 16 + colr;
        #pragma unroll
        for (int r = 0; r < 4; ++r) {
            float v = (c < NSEQ) ? expf(s[j][r] - mx[r]) : 0.f;
            s[j][r] = v;
            sum[r] += v;
        }
    }
    #pragma unroll
    for (int off = 1; off <= 8; off <<= 1)
        #pragma unroll
        for (int r = 0; r < 4; ++r)
            sum[r] += __shfl_xor(sum[r], off);
    float inv[4];
    #pragma unroll
    for (int r = 0; r < 4; ++r) inv[r] = 1.0f / sum[r];

    __syncthreads();                 // all waves done reading Ks
    short* P = Ks;                   // overlay: [64 rows][224 k] bf16
    #pragma unroll
    for (int j = 0; j < 14; ++j)
        #pragma unroll
        for (int r = 0; r < 4; ++r)
            P[(wave * 16 + quad * 4 + r) * 224 + j * 16 + colr] =
                f2bf(s[j][r] * inv[r]);

    // ---- O = P @ V : per wave 16 rows x 64 dims, K=224 ----
    f32x4 o[4];
    #pragma unroll
    for (int j2 = 0; j2 < 4; ++j2) o[j2] = (f32x4){0.f, 0.f, 0.f, 0.f};
    #pragma unroll
    for (int ks = 0; ks < 7; ++ks) {
        s8v a = *(const s8v*)&P[(wave * 16 + colr) * 224 + quad * 8 + ks * 32];
        #pragma unroll
        for (int j2 = 0; j2 < 4; ++j2) {
            s8v bf = *(const s8v*)&Vt[(j2 * 16 + colr) * 224 + quad * 8 + ks * 32];
            o[j2] = __builtin_amdgcn_mfma_f32_16x16x32_bf16(a, bf, o[j2], 0, 0, 0);
        }
    }

    #pragma unroll
    for (int j2 = 0; j2 < 4; ++j2)
        #pragma unroll
        for (int r = 0; r < 4; ++r) {
            int qrow = q0 + wave * 16 + quad * 4 + r;
            if (qrow < NSEQ)
                O[((long)b * NSEQ + qrow) * DIM + h * DH + j2 * 16 + colr] =
                    __float2bfloat16(o[j2][r]);
        }
}

// ------------------------------------------------- weight transpose->bf16 ---
__global__ __launch_bounds__(256)
void wconv_kernel(const float* __restrict__ in, bf16* __restrict__ out,
                  int R, int C)
{
    __shared__ float t[32][33];
    int c0 = blockIdx.x * 32, r0 = blockIdx.y * 32;
    int tx = threadIdx.x & 31, ty = threadIdx.x >> 5;
    #pragma unroll
    for (int i = 0; i < 4; ++i) {
        int r = r0 + ty + 8 * i;
        if (r < R && c0 + tx < C) t[ty + 8 * i][tx] = in[(long)r * C + c0 + tx];
    }
    __syncthreads();
    #pragma unroll
    for (int i = 0; i < 4; ++i) {
        int c = c0 + ty + 8 * i;
        int r = r0 + tx;
        if (c < C && r < R) out[(long)c * R + r] = __float2bfloat16(t[tx][ty + 8 * i]);
    }
}

// ---------------------------------------------------------------- LayerNorm -
__global__ __launch_bounds__(256)
void ln_kernel(const float* __restrict__ in, long in_stride,
               bf16* __restrict__ out, long out_stride,
               const float* __restrict__ w, const float* __restrict__ b)
{
    long r = blockIdx.x;
    const float* x = in + r * in_stride;
    bf16* y = out + r * out_stride;
    int tid = threadIdx.x;

    float s = 0.f, s2 = 0.f;
    for (int i = tid; i < DIM; i += 256) {
        float v = x[i];
        s += v; s2 += v * v;
    }
    #pragma unroll
    for (int off = 32; off > 0; off >>= 1) {
        s  += __shfl_down(s, off);
        s2 += __shfl_down(s2, off);
    }
    __shared__ float red[2][4];
    int wave = tid >> 6, lane = tid & 63;
    if (lane == 0) { red[0][wave] = s; red[1][wave] = s2; }
    __syncthreads();
    if (tid == 0) {
        float t  = red[0][0] + red[0][1] + red[0][2] + red[0][3];
        float t2 = red[1][0] + red[1][1] + red[1][2] + red[1][3];
        float mean = t / (float)DIM;
        float var  = t2 / (float)DIM - mean * mean;
        red[0][0] = mean;
        red[1][0] = 1.0f / sqrtf(var + 1e-6f);
    }
    __syncthreads();
    float mean = red[0][0], rstd = red[1][0];
    for (int i = tid; i < DIM; i += 256)
        y[i] = __float2bfloat16((x[i] - mean) * rstd * w[i] + b[i]);
}

// ---------------------------------------------------------------- im2col ----
__global__ __launch_bounds__(256)
void im2col_kernel(const float* __restrict__ x, bf16* __restrict__ out)
{
    long i = (long)blockIdx.x * 256 + threadIdx.x;
    const long total = (long)BV * NPAT * DIM;
    if (i >= total) return;
    int col = (int)(i % DIM);
    long row = i / DIM;
    int c  = col >> 8;
    int py = (col >> 4) & 15;
    int px = col & 15;
    int b  = (int)(row / NPAT);
    int pp = (int)(row % NPAT);
    int gy = pp / 14, gx = pp % 14;
    out[i] = __float2bfloat16(
        x[(((long)(b * 3 + c) * 224 + gy * 16 + py) * 224) + gx * 16 + px]);
}

// ---------------------------------------------------------------- assemble --
__global__ __launch_bounds__(256)
void assemble_kernel(const float* __restrict__ tmp, const float* __restrict__ cls,
                     const float* __restrict__ pos, float* __restrict__ h)
{
    long i = (long)blockIdx.x * 256 + threadIdx.x;
    const long total = (long)BV * NSEQ * DIM;
    if (i >= total) return;
    int d = (int)(i % DIM);
    long row = i / DIM;
    int n = (int)(row % NSEQ);
    long b = row / NSEQ;
    float v;
    if (n == 0) v = cls[d];
    else        v = tmp[(b * NPAT + (n - 1)) * DIM + d];
    h[i] = v + pos[(long)n * DIM + d];
}

// ---------------------------------------------------------------- launch ----
extern "C" void kernel_launch(void* const* d_in, const int* in_sizes, int n_in,
                              void* d_out, int out_size, void* d_ws, size_t ws_size,
                              hipStream_t stream)
{
    const float* x        = (const float*)d_in[0];
    const float* patch_w  = (const float*)d_in[1];
    const float* patch_b  = (const float*)d_in[2];
    const float* cls_tok  = (const float*)d_in[3];
    const float* pos_emb  = (const float*)d_in[4];
    const float* ln1_w    = (const float*)d_in[5];
    const float* ln1_b    = (const float*)d_in[6];
    const float* qkv_w    = (const float*)d_in[7];
    const float* qkv_b    = (const float*)d_in[8];
    const float* proj_w   = (const float*)d_in[9];
    const float* proj_b   = (const float*)d_in[10];
    const float* ln2_w    = (const float*)d_in[11];
    const float* ln2_b    = (const float*)d_in[12];
    const float* fc1_w    = (const float*)d_in[13];
    const float* fc1_b    = (const float*)d_in[14];
    const float* fc2_w    = (const float*)d_in[15];
    const float* fc2_b    = (const float*)d_in[16];
    const float* normf_w  = (const float*)d_in[17];
    const float* normf_b  = (const float*)d_in[18];
    const float* head_w   = (const float*)d_in[19];
    const float* head_b   = (const float*)d_in[20];
    float* out = (float*)d_out;

    const long M = (long)BV * NSEQ;   // 6304
    const long MP = (long)BV * NPAT;  // 6272

    // ---- workspace layout ----
    float* h      = (float*)d_ws;                 // [6304][768] fp32
    float* ptmp   = h + 4841472L;                 // patch-embed tmp fp32 [6272][768]
    bf16*  qkv    = (bf16*)(ptmp + 4816896L);     // [6304][2304] bf16
    bf16*  lnout  = qkv + 14524416L;              // [6304][768] bf16 (ln out / O)
    bf16*  big    = lnout + 4841472L;             // [6304][3072] bf16 (patches/mlp)
    bf16*  wT     = big + 19365888L;              // per-layer transposed weights
    bf16*  qkvT = wT;                             // [2304][768]
    bf16*  projT = wT + 1769472L;                 // [768][768]
    bf16*  fc1T  = wT + 2359296L;                 // [3072][768]
    bf16*  fc2T  = wT + 4718592L;                 // [768][3072]

    dim3 blk(256);

    // ---- patch embed ----
    wconv_kernel<<<dim3(24, 24), blk, 0, stream>>>(patch_w, qkvT, DIM, DIM);
    im2col_kernel<<<dim3((unsigned)((MP * DIM + 255) / 256)), blk, 0, stream>>>(x, big);
    bgemm<0, false, float><<<dim3(6, 49), blk, 0, stream>>>(
        big, qkvT, patch_b, ptmp, (int)MP, DIM, DIM, DIM, DIM, DIM);
    assemble_kernel<<<dim3((unsigned)((M * DIM + 255) / 256)), blk, 0, stream>>>(
        ptmp, cls_tok, pos_emb, h);

    // ---- transformer blocks ----
    for (int l = 0; l < NLAYER; ++l) {
        wconv_kernel<<<dim3(72, 24), blk, 0, stream>>>(
            qkv_w + (long)l * DIM * 3 * DIM, qkvT, DIM, 3 * DIM);
        wconv_kernel<<<dim3(24, 24), blk, 0, stream>>>(
            proj_w + (long)l * DIM * DIM, projT, DIM, DIM);
        wconv_kernel<<<dim3(96, 24), blk, 0, stream>>>(
            fc1_w + (long)l * DIM * MLPD, fc1T, DIM, MLPD);
        wconv_kernel<<<dim3(24, 96), blk, 0, stream>>>(
            fc2_w + (long)l * MLPD * DIM, fc2T, MLPD, DIM);

        // LN1: h -> lnout (bf16)
        ln_kernel<<<dim3((unsigned)M), blk, 0, stream>>>(
            h, DIM, lnout, DIM, ln1_w + (long)l * DIM, ln1_b + (long)l * DIM);

        // QKV: lnout @ qkvT^T + qb -> qkv (bf16)
        bgemm<0, false, bf16><<<dim3(18, 50), blk, 0, stream>>>(
            lnout, qkvT, qkv_b + (long)l * 3 * DIM, qkv,
            (int)M, 3 * DIM, DIM, DIM, DIM, 3 * DIM);

        // fused attention -> lnout (bf16 O)
        attn_kernel<<<dim3(4, BV * NHD), blk, 0, stream>>>(qkv, lnout);

        // proj: h += O @ projT^T + pb
        bgemm<0, true, float><<<dim3(6, 50), blk, 0, stream>>>(
            lnout, projT, proj_b + (long)l * DIM, h,
            (int)M, DIM, DIM, DIM, DIM, DIM);

        // LN2: h -> lnout (bf16)
        ln_kernel<<<dim3((unsigned)M), blk, 0, stream>>>(
            h, DIM, lnout, DIM, ln2_w + (long)l * DIM, ln2_b + (long)l * DIM);

        // FC1 + GELU -> big (bf16)
        bgemm<1, false, bf16><<<dim3(24, 50), blk, 0, stream>>>(
            lnout, fc1T, fc1_b + (long)l * MLPD, big,
            (int)M, MLPD, DIM, DIM, DIM, MLPD);

        // FC2: h += big @ fc2T^T + f2b
        bgemm<0, true, float><<<dim3(6, 50), blk, 0, stream>>>(
            big, fc2T, fc2_b + (long)l * DIM, h,
            (int)M, DIM, MLPD, MLPD, MLPD, DIM);
    }

    // ---- final LN on cls rows -> lnout[0:32] (bf16) ----
    ln_kernel<<<dim3(BV), blk, 0, stream>>>(
        h, (long)NSEQ * DIM, lnout, DIM, normf_w, normf_b);

    // ---- head ----
    wconv_kernel<<<dim3(32, 24), blk, 0, stream>>>(head_w, qkvT, DIM, NCLS);
    bgemm<0, false, float><<<dim3(8, 1), blk, 0, stream>>>(
        lnout, qkvT, head_b, out, BV, NCLS, DIM, DIM, DIM, NCLS);
}

// Round 3
// 3111.609 us; speedup vs baseline: 1.0416x; 1.0416x over previous
//
#include <hip/hip_runtime.h>
#include <hip/hip_bf16.h>
#include <type_traits>

// ViT-Base/16 forward. Round 6: (1) MI-templated bgemm — 64-row tile for the
// grid-starved N=768 GEMMs (proj/fc2/patch/head), (2) batched per-layer wconv
// (4 launches -> 1), (3) wave-per-row LayerNorm (no barriers), (4) attn Q in
// registers. Keeps R4 counted-vmcnt pipeline + R5 LDS XOR-swizzle.

#define BV   32
#define DIM  768
#define NHD  12
#define DH   64
#define NSEQ 197
#define NPAT 196
#define MLPD 3072
#define NCLS 1000
#define NLAYER 12

typedef __hip_bfloat16 bf16;
typedef __attribute__((ext_vector_type(8))) short s8v;    // 8 bf16 (4 VGPRs)
typedef __attribute__((ext_vector_type(4))) float f32x4;  // MFMA acc

#define GLDS16(gp, lp) __builtin_amdgcn_global_load_lds( \
    (const __attribute__((address_space(1))) void*)(gp), \
    (__attribute__((address_space(3))) void*)(lp), 16, 0, 0)

__device__ __forceinline__ short f2bf(float v) {
    return (short)__bfloat16_as_ushort(__float2bfloat16(v));
}

// ------------------------------------------------------------- MFMA GEMM ----
// C[M,N] = epilogue(A @ B^T + bias), A: [M,K] bf16 (lda), B: [N,K] bf16 (ldb),
// both K-contiguous. TO = float or bf16. ACT=1 -> exact GELU. RESID (float
// only): C += result. K % 32 == 0. Tile (MI*32)x128, BK=32, 4 waves (2x2).
// MI=4: 128x128 (3 bufs = 48 KB, 3 blk/CU). MI=2: 64x128 (36 KB, 4 blk/CU) —
// for grid-starved N=768 shapes (proj/fc2/patch/head: 300 blocks -> 594).
// K-loop: 3-deep LDS pipeline (counted vmcnt) + XOR-swizzled tiles.
template<int ACT, bool RESID, typename TO, int MI>
__global__ __launch_bounds__(256)
void bgemm(const bf16* __restrict__ A, const bf16* __restrict__ B,
           const float* __restrict__ bias, TO* __restrict__ C,
           int M, int N, int K, int lda, int ldb, int ldc)
{
    constexpr int BM    = MI * 32;          // rows per block tile
    constexpr int ASIZE = MI * 1024;        // shorts per A tile
    constexpr int BUFS  = ASIZE + 4096;     // shorts per (A|B) buffer
    __shared__ short As[3 * BUFS];

    // XCD-aware swizzle: balanced bijection, XCD x owns a contiguous range.
    int nbx = gridDim.x;
    int nb  = nbx * gridDim.y;
    int bid = blockIdx.y * nbx + blockIdx.x;
    {
        int per = nb >> 3, rem = nb & 7;
        int x = bid & 7, loc = bid >> 3;
        bid = x * per + (x < rem ? x : rem) + loc;
    }
    const int m0 = (bid / nbx) * BM;
    const int n0 = (bid % nbx) * 128;

    const int tid  = threadIdx.x;
    const int wave = tid >> 6;
    const int lane = tid & 63;

    const int c0 = wave * 2, c1 = c0 + 1;
    const int rsub = lane >> 2;
    // T2: pre-swizzled source column (involution)
    const int kp8  = (((lane & 3) ^ ((rsub >> 1) & 3)) * 8);

    // A-chunk rows: MI=4 -> wave stages chunks c0,c1; MI=2 -> chunk `wave`.
    int ra0, ra1;
    if constexpr (MI == 4) { ra0 = m0 + c0 * 16 + rsub; ra1 = m0 + c1 * 16 + rsub; }
    else                   { ra0 = m0 + wave * 16 + rsub; ra1 = ra0; }
    if (ra0 > M - 1) ra0 = M - 1;
    if (ra1 > M - 1) ra1 = M - 1;
    int rb0 = n0 + c0 * 16 + rsub; if (rb0 > N - 1) rb0 = N - 1;
    int rb1 = n0 + c1 * 16 + rsub; if (rb1 > N - 1) rb1 = N - 1;

    const bf16* pa0 = A + (long)ra0 * lda + kp8;
    const bf16* pa1 = A + (long)ra1 * lda + kp8;
    const bf16* pb0 = B + (long)rb0 * ldb + kp8;
    const bf16* pb1 = B + (long)rb1 * ldb + kp8;

    const int wm = wave >> 1, wn = wave & 1;
    const int colr = lane & 15;
    const int quad = lane >> 4;

    f32x4 acc[MI][4];
    #pragma unroll
    for (int i = 0; i < MI; ++i)
        #pragma unroll
        for (int j = 0; j < 4; ++j)
            acc[i][j] = (f32x4){0.f, 0.f, 0.f, 0.f};

    // T2: swizzled fragment-read slot
    const int sq = quad ^ ((colr >> 1) & 3);
    const short* AsP = &As[(wm * (MI * 16) + colr) * 32 + sq * 8];
    const short* BsP = &As[ASIZE + (wn * 64 + colr) * 32 + sq * 8];

    auto STAGE = [&](int bufi) {
        int _o = bufi * BUFS;
        if constexpr (MI == 4) {
            GLDS16(pa0, &As[_o + c0 * 512]);
            GLDS16(pa1, &As[_o + c1 * 512]);
            pa1 += 32;
        } else {
            GLDS16(pa0, &As[_o + wave * 512]);
        }
        GLDS16(pb0, &As[_o + ASIZE + c0 * 512]);
        GLDS16(pb1, &As[_o + ASIZE + c1 * 512]);
        pa0 += 32; pb0 += 32; pb1 += 32;
    };

    const int nt = K >> 5;        // K / 32
    STAGE(0);
    STAGE(1);
    int cur = 0, nxt = 2;

    for (int t = 0; t < nt; ++t) {
        if (t + 2 < nt) {
            STAGE(nxt);
            nxt = (nxt == 2) ? 0 : nxt + 1;
            // 2 newer stages stay in flight; tile t's loads are done.
            if constexpr (MI == 4) asm volatile("s_waitcnt vmcnt(8)" ::: "memory");
            else                   asm volatile("s_waitcnt vmcnt(6)" ::: "memory");
        } else if (t + 1 < nt) {
            if constexpr (MI == 4) asm volatile("s_waitcnt vmcnt(4)" ::: "memory");
            else                   asm volatile("s_waitcnt vmcnt(3)" ::: "memory");
        } else {
            asm volatile("s_waitcnt vmcnt(0)" ::: "memory");
        }
        __builtin_amdgcn_s_barrier();            // tile t visible to all waves
        asm volatile("" ::: "memory");

        const short* Ab = AsP + cur * BUFS;
        const short* Bb = BsP + cur * BUFS;
        s8v a[MI], b[4];
        #pragma unroll
        for (int i = 0; i < MI; ++i) a[i] = *(const s8v*)(Ab + i * 512);
        #pragma unroll
        for (int j = 0; j < 4; ++j) b[j] = *(const s8v*)(Bb + j * 512);
        #pragma unroll
        for (int i = 0; i < MI; ++i)
            #pragma unroll
            for (int j = 0; j < 4; ++j)
                acc[i][j] = __builtin_amdgcn_mfma_f32_16x16x32_bf16(
                    a[i], b[j], acc[i][j], 0, 0, 0);

        cur = (cur == 2) ? 0 : cur + 1;
        asm volatile("" ::: "memory");
        __builtin_amdgcn_s_barrier();            // buf[cur] free to overwrite
        asm volatile("" ::: "memory");
    }

    // ---- epilogue: per-wave LDS transpose -> vectorized stores ----
    // C/D layout: col = lane&15, row = quad*4 + reg   [m89-verified]
    float* ep = ((float*)As) + wave * 1024;   // 16x64 fp32 per wave
    const int lrow = lane >> 2;
    const int lc4  = (lane & 3) * 16;

    #pragma unroll
    for (int i = 0; i < MI; ++i) {
        #pragma unroll
        for (int j = 0; j < 4; ++j)
            #pragma unroll
            for (int r = 0; r < 4; ++r)
                ep[(quad * 4 + r) * 64 + j * 16 + colr] = acc[i][j][r];
        __syncthreads();

        int gm = m0 + wm * (MI * 16) + i * 16 + lrow;
        int gn = n0 + wn * 64 + lc4;
        if (gm < M) {
            float vals[16];
            #pragma unroll
            for (int c = 0; c < 16; ++c) vals[c] = ep[lrow * 64 + lc4 + c];

            if (gn + 16 <= N) {
                if (bias) {
                    #pragma unroll
                    for (int c = 0; c < 16; ++c) vals[c] += bias[gn + c];
                }
                if (ACT == 1) {
                    #pragma unroll
                    for (int c = 0; c < 16; ++c)
                        vals[c] = 0.5f * vals[c] *
                                  (1.0f + erff(vals[c] * 0.70710678118654752f));
                }
                if constexpr (std::is_same<TO, float>::value) {
                    float* Cp = (float*)C + (long)gm * ldc + gn;
                    if constexpr (RESID) {
                        #pragma unroll
                        for (int c4 = 0; c4 < 4; ++c4) {
                            f32x4 old = *(const f32x4*)&Cp[c4 * 4];
                            #pragma unroll
                            for (int e = 0; e < 4; ++e) vals[c4 * 4 + e] += old[e];
                        }
                    }
                    #pragma unroll
                    for (int c4 = 0; c4 < 4; ++c4) {
                        f32x4 v;
                        #pragma unroll
                        for (int e = 0; e < 4; ++e) v[e] = vals[c4 * 4 + e];
                        *(f32x4*)&Cp[c4 * 4] = v;
                    }
                } else {
                    short* Cp = (short*)C + (long)gm * ldc + gn;
                    s8v v0, v1;
                    #pragma unroll
                    for (int e = 0; e < 8; ++e) { v0[e] = f2bf(vals[e]); v1[e] = f2bf(vals[8 + e]); }
                    *(s8v*)&Cp[0] = v0;
                    *(s8v*)&Cp[8] = v1;
                }
            } else {
                // partial-N fallback (head GEMM, N=1000)
                #pragma unroll
                for (int c = 0; c < 16; ++c) {
                    int g = gn + c;
                    if (g >= N) continue;
                    float v = vals[c];
                    if (bias) v += bias[g];
                    if (ACT == 1) v = 0.5f * v * (1.0f + erff(v * 0.70710678118654752f));
                    long idx = (long)gm * ldc + g;
                    if constexpr (RESID) v += ((const float*)C)[idx];
                    if constexpr (std::is_same<TO, float>::value) C[idx] = v;
                    else C[idx] = __float2bfloat16(v);
                }
            }
        }
        __syncthreads();
    }
}

// --------------------------------------------------- fused flash attention --
// One WG (4 waves) per (b, h, 64-row Q tile). qkv: [B*197][2304] bf16
// (q|k|v, head-contig 64). O: [B*197][768] bf16. Q lives in registers.
__global__ __launch_bounds__(256)
void attn_kernel(const bf16* __restrict__ qkv, bf16* __restrict__ O)
{
    __shared__ short Ks[224 * 72];   // +8 pad; P (64x224) overlays after S-phase
    __shared__ short Vt[64 * 224];   // V transposed [d][seq]

    const int tid  = threadIdx.x;
    const int wave = tid >> 6;
    const int lane = tid & 63;
    const int q0 = blockIdx.x * 64;
    const int b  = blockIdx.y / NHD;
    const int h  = blockIdx.y % NHD;
    const bf16* base = qkv + (long)b * NSEQ * (3 * DIM);

    const int colr = lane & 15;
    const int quad = lane >> 4;

    // ---- Q fragments straight to registers (issued first, overlap staging) --
    int qr = q0 + wave * 16 + colr; if (qr > NSEQ - 1) qr = NSEQ - 1;
    const bf16* qp = &base[(long)qr * (3 * DIM) + h * DH + quad * 8];
    s8v qa0 = *(const s8v*)qp;
    s8v qa1 = *(const s8v*)(qp + 32);

    // ---- stage K (224x64, clamped), Vt (64x224, clamped) ----
    #pragma unroll
    for (int p = 0; p < 7; ++p) {
        int idx = p * 2048 + tid * 8;
        int row = idx >> 6, col = idx & 63;
        int gr = row; if (gr > NSEQ - 1) gr = NSEQ - 1;
        *(s8v*)&Ks[row * 72 + col] =
            *(const s8v*)&base[(long)gr * (3 * DIM) + DIM + h * DH + col];
    }
    {
        int seqL = tid & 31, dc = tid >> 5;   // dc 0..7
        #pragma unroll
        for (int st = 0; st < 7; ++st) {
            int seq = st * 32 + seqL;
            int gr = seq; if (gr > NSEQ - 1) gr = NSEQ - 1;
            s8v v = *(const s8v*)&base[(long)gr * (3 * DIM) + 2 * DIM + h * DH + dc * 8];
            #pragma unroll
            for (int i = 0; i < 8; ++i)
                Vt[(dc * 8 + i) * 224 + seq] = v[i];
        }
    }
    __syncthreads();

    // ---- S = Q @ K^T : each wave = 16 rows x 224 cols, K=64 ----
    f32x4 s[14];
    #pragma unroll
    for (int j = 0; j < 14; ++j) s[j] = (f32x4){0.f, 0.f, 0.f, 0.f};
    #pragma unroll
    for (int j = 0; j < 14; ++j) {
        s8v bf0 = *(const s8v*)&Ks[(j * 16 + colr) * 72 + quad * 8];
        s[j] = __builtin_amdgcn_mfma_f32_16x16x32_bf16(qa0, bf0, s[j], 0, 0, 0);
        s8v bf1 = *(const s8v*)&Ks[(j * 16 + colr) * 72 + quad * 8 + 32];
        s[j] = __builtin_amdgcn_mfma_f32_16x16x32_bf16(qa1, bf1, s[j], 0, 0, 0);
    }

    // ---- softmax (rows: quad*4+r within wave slice; col: j*16+colr) ----
    float mx[4] = {-1e30f, -1e30f, -1e30f, -1e30f};
    #pragma unroll
    for (int j = 0; j < 14; ++j) {
        int c = j * 16 + colr;
        #pragma unroll
        for (int r = 0; r < 4; ++r) {
            s[j][r] *= 0.125f;
            if (c < NSEQ) mx[r] = fmaxf(mx[r], s[j][r]);
        }
    }
    #pragma unroll
    for (int off = 1; off <= 8; off <<= 1)
        #pragma unroll
        for (int r = 0; r < 4; ++r)
            mx[r] = fmaxf(mx[r], __shfl_xor(mx[r], off));

    float sum[4] = {0.f, 0.f, 0.f, 0.f};
    #pragma unroll
    for (int j = 0; j < 14; ++j) {
        int c = j * 16 + colr;
        #pragma unroll
        for (int r = 0; r < 4; ++r) {
            float v = (c < NSEQ) ? expf(s[j][r] - mx[r]) : 0.f;
            s[j][r] = v;
            sum[r] += v;
        }
    }
    #pragma unroll
    for (int off = 1; off <= 8; off <<= 1)
        #pragma unroll
        for (int r = 0; r < 4; ++r)
            sum[r] += __shfl_xor(sum[r], off);
    float inv[4];
    #pragma unroll
    for (int r = 0; r < 4; ++r) inv[r] = 1.0f / sum[r];

    __syncthreads();                 // all waves done reading Ks
    short* P = Ks;                   // overlay: [64 rows][224 k] bf16
    #pragma unroll
    for (int j = 0; j < 14; ++j)
        #pragma unroll
        for (int r = 0; r < 4; ++r)
            P[(wave * 16 + quad * 4 + r) * 224 + j * 16 + colr] =
                f2bf(s[j][r] * inv[r]);

    __syncthreads();

    // ---- O = P @ V : per wave 16 rows x 64 dims, K=224 ----
    f32x4 o[4];
    #pragma unroll
    for (int j2 = 0; j2 < 4; ++j2) o[j2] = (f32x4){0.f, 0.f, 0.f, 0.f};
    #pragma unroll
    for (int ks = 0; ks < 7; ++ks) {
        s8v a = *(const s8v*)&P[(wave * 16 + colr) * 224 + quad * 8 + ks * 32];
        #pragma unroll
        for (int j2 = 0; j2 < 4; ++j2) {
            s8v bf = *(const s8v*)&Vt[(j2 * 16 + colr) * 224 + quad * 8 + ks * 32];
            o[j2] = __builtin_amdgcn_mfma_f32_16x16x32_bf16(a, bf, o[j2], 0, 0, 0);
        }
    }

    #pragma unroll
    for (int j2 = 0; j2 < 4; ++j2)
        #pragma unroll
        for (int r = 0; r < 4; ++r) {
            int qrow = q0 + wave * 16 + quad * 4 + r;
            if (qrow < NSEQ)
                O[((long)b * NSEQ + qrow) * DIM + h * DH + j2 * 16 + colr] =
                    __float2bfloat16(o[j2][r]);
        }
}

// ------------------------------------------------- weight transpose->bf16 ---
__device__ __forceinline__ void wconv_tile(const float* __restrict__ in,
                                           bf16* __restrict__ out,
                                           int R, int C, int bx, int by)
{
    __shared__ float t[32][33];
    int c0 = bx * 32, r0 = by * 32;
    int tx = threadIdx.x & 31, ty = threadIdx.x >> 5;
    #pragma unroll
    for (int i = 0; i < 4; ++i) {
        int r = r0 + ty + 8 * i;
        if (r < R && c0 + tx < C) t[ty + 8 * i][tx] = in[(long)r * C + c0 + tx];
    }
    __syncthreads();
    #pragma unroll
    for (int i = 0; i < 4; ++i) {
        int c = c0 + ty + 8 * i;
        int r = r0 + tx;
        if (c < C && r < R) out[(long)c * R + r] = __float2bfloat16(t[tx][ty + 8 * i]);
    }
}

__global__ __launch_bounds__(256)
void wconv_kernel(const float* __restrict__ in, bf16* __restrict__ out,
                  int R, int C)
{
    wconv_tile(in, out, R, C, blockIdx.x, blockIdx.y);
}

// All four per-layer weight transposes in one launch (segmented grid).
__global__ __launch_bounds__(256)
void wconv4_kernel(const float* __restrict__ qw, const float* __restrict__ pw,
                   const float* __restrict__ f1w, const float* __restrict__ f2w,
                   bf16* __restrict__ qT, bf16* __restrict__ pT,
                   bf16* __restrict__ f1T, bf16* __restrict__ f2T)
{
    int bid = blockIdx.x;
    if (bid < 1728)      { int t = bid;        wconv_tile(qw,  qT,  768,  2304, t % 72, t / 72); }
    else if (bid < 2304) { int t = bid - 1728; wconv_tile(pw,  pT,  768,  768,  t % 24, t / 24); }
    else if (bid < 4608) { int t = bid - 2304; wconv_tile(f1w, f1T, 768,  3072, t % 96, t / 96); }
    else                 { int t = bid - 4608; wconv_tile(f2w, f2T, 3072, 768,  t % 24, t / 24); }
}

// ---------------------------------------------------------------- LayerNorm -
// One wave per row (DIM=768 = 64 lanes x 12), 4 rows per block. No LDS/barrier.
__global__ __launch_bounds__(256)
void ln_kernel(const float* __restrict__ in, long in_stride,
               bf16* __restrict__ out, long out_stride,
               const float* __restrict__ w, const float* __restrict__ b,
               int nrows)
{
    int wave = threadIdx.x >> 6, lane = threadIdx.x & 63;
    long r = (long)blockIdx.x * 4 + wave;
    if (r >= nrows) return;
    const float* x = in + r * in_stride;
    bf16* y = out + r * out_stride;

    f32x4 c[3];
    float s = 0.f, s2 = 0.f;
    #pragma unroll
    for (int p = 0; p < 3; ++p) {
        c[p] = *(const f32x4*)&x[p * 256 + lane * 4];
        #pragma unroll
        for (int e = 0; e < 4; ++e) { s += c[p][e]; s2 += c[p][e] * c[p][e]; }
    }
    #pragma unroll
    for (int off = 1; off <= 32; off <<= 1) {
        s  += __shfl_xor(s, off);
        s2 += __shfl_xor(s2, off);
    }
    float mean = s * (1.0f / (float)DIM);
    float var  = s2 * (1.0f / (float)DIM) - mean * mean;
    float rstd = 1.0f / sqrtf(var + 1e-6f);

    #pragma unroll
    for (int p = 0; p < 3; ++p) {
        f32x4 wv = *(const f32x4*)&w[p * 256 + lane * 4];
        f32x4 bv = *(const f32x4*)&b[p * 256 + lane * 4];
        #pragma unroll
        for (int e = 0; e < 4; ++e)
            y[p * 256 + lane * 4 + e] =
                __float2bfloat16((c[p][e] - mean) * rstd * wv[e] + bv[e]);
    }
}

// ---------------------------------------------------------------- im2col ----
__global__ __launch_bounds__(256)
void im2col_kernel(const float* __restrict__ x, bf16* __restrict__ out)
{
    long i = (long)blockIdx.x * 256 + threadIdx.x;
    const long total = (long)BV * NPAT * DIM;
    if (i >= total) return;
    int col = (int)(i % DIM);
    long row = i / DIM;
    int c  = col >> 8;
    int py = (col >> 4) & 15;
    int px = col & 15;
    int b  = (int)(row / NPAT);
    int pp = (int)(row % NPAT);
    int gy = pp / 14, gx = pp % 14;
    out[i] = __float2bfloat16(
        x[(((long)(b * 3 + c) * 224 + gy * 16 + py) * 224) + gx * 16 + px]);
}

// ---------------------------------------------------------------- assemble --
__global__ __launch_bounds__(256)
void assemble_kernel(const float* __restrict__ tmp, const float* __restrict__ cls,
                     const float* __restrict__ pos, float* __restrict__ h)
{
    long i = (long)blockIdx.x * 256 + threadIdx.x;
    const long total = (long)BV * NSEQ * DIM;
    if (i >= total) return;
    int d = (int)(i % DIM);
    long row = i / DIM;
    int n = (int)(row % NSEQ);
    long b = row / NSEQ;
    float v;
    if (n == 0) v = cls[d];
    else        v = tmp[(b * NPAT + (n - 1)) * DIM + d];
    h[i] = v + pos[(long)n * DIM + d];
}

// ---------------------------------------------------------------- launch ----
extern "C" void kernel_launch(void* const* d_in, const int* in_sizes, int n_in,
                              void* d_out, int out_size, void* d_ws, size_t ws_size,
                              hipStream_t stream)
{
    const float* x        = (const float*)d_in[0];
    const float* patch_w  = (const float*)d_in[1];
    const float* patch_b  = (const float*)d_in[2];
    const float* cls_tok  = (const float*)d_in[3];
    const float* pos_emb  = (const float*)d_in[4];
    const float* ln1_w    = (const float*)d_in[5];
    const float* ln1_b    = (const float*)d_in[6];
    const float* qkv_w    = (const float*)d_in[7];
    const float* qkv_b    = (const float*)d_in[8];
    const float* proj_w   = (const float*)d_in[9];
    const float* proj_b   = (const float*)d_in[10];
    const float* ln2_w    = (const float*)d_in[11];
    const float* ln2_b    = (const float*)d_in[12];
    const float* fc1_w    = (const float*)d_in[13];
    const float* fc1_b    = (const float*)d_in[14];
    const float* fc2_w    = (const float*)d_in[15];
    const float* fc2_b    = (const float*)d_in[16];
    const float* normf_w  = (const float*)d_in[17];
    const float* normf_b  = (const float*)d_in[18];
    const float* head_w   = (const float*)d_in[19];
    const float* head_b   = (const float*)d_in[20];
    float* out = (float*)d_out;

    const long M = (long)BV * NSEQ;   // 6304
    const long MP = (long)BV * NPAT;  // 6272

    // ---- workspace layout ----
    float* h      = (float*)d_ws;                 // [6304][768] fp32
    float* ptmp   = h + 4841472L;                 // patch-embed tmp fp32 [6272][768]
    bf16*  qkv    = (bf16*)(ptmp + 4816896L);     // [6304][2304] bf16
    bf16*  lnout  = qkv + 14524416L;              // [6304][768] bf16 (ln out / O)
    bf16*  big    = lnout + 4841472L;             // [6304][3072] bf16 (patches/mlp)
    bf16*  wT     = big + 19365888L;              // per-layer transposed weights
    bf16*  qkvT = wT;                             // [2304][768]
    bf16*  projT = wT + 1769472L;                 // [768][768]
    bf16*  fc1T  = wT + 2359296L;                 // [3072][768]
    bf16*  fc2T  = wT + 4718592L;                 // [768][3072]

    dim3 blk(256);

    // ---- patch embed ----
    wconv_kernel<<<dim3(24, 24), blk, 0, stream>>>(patch_w, qkvT, DIM, DIM);
    im2col_kernel<<<dim3((unsigned)((MP * DIM + 255) / 256)), blk, 0, stream>>>(x, big);
    bgemm<0, false, float, 2><<<dim3(6, 98), blk, 0, stream>>>(
        big, qkvT, patch_b, ptmp, (int)MP, DIM, DIM, DIM, DIM, DIM);
    assemble_kernel<<<dim3((unsigned)((M * DIM + 255) / 256)), blk, 0, stream>>>(
        ptmp, cls_tok, pos_emb, h);

    // ---- transformer blocks ----
    for (int l = 0; l < NLAYER; ++l) {
        wconv4_kernel<<<dim3(6912), blk, 0, stream>>>(
            qkv_w + (long)l * DIM * 3 * DIM, proj_w + (long)l * DIM * DIM,
            fc1_w + (long)l * DIM * MLPD,    fc2_w + (long)l * MLPD * DIM,
            qkvT, projT, fc1T, fc2T);

        // LN1: h -> lnout (bf16)
        ln_kernel<<<dim3((unsigned)((M + 3) / 4)), blk, 0, stream>>>(
            h, DIM, lnout, DIM, ln1_w + (long)l * DIM, ln1_b + (long)l * DIM, (int)M);

        // QKV: lnout @ qkvT^T + qb -> qkv (bf16)
        bgemm<0, false, bf16, 4><<<dim3(18, 50), blk, 0, stream>>>(
            lnout, qkvT, qkv_b + (long)l * 3 * DIM, qkv,
            (int)M, 3 * DIM, DIM, DIM, DIM, 3 * DIM);

        // fused attention -> lnout (bf16 O)
        attn_kernel<<<dim3(4, BV * NHD), blk, 0, stream>>>(qkv, lnout);

        // proj: h += O @ projT^T + pb
        bgemm<0, true, float, 2><<<dim3(6, 99), blk, 0, stream>>>(
            lnout, projT, proj_b + (long)l * DIM, h,
            (int)M, DIM, DIM, DIM, DIM, DIM);

        // LN2: h -> lnout (bf16)
        ln_kernel<<<dim3((unsigned)((M + 3) / 4)), blk, 0, stream>>>(
            h, DIM, lnout, DIM, ln2_w + (long)l * DIM, ln2_b + (long)l * DIM, (int)M);

        // FC1 + GELU -> big (bf16)
        bgemm<1, false, bf16, 4><<<dim3(24, 50), blk, 0, stream>>>(
            lnout, fc1T, fc1_b + (long)l * MLPD, big,
            (int)M, MLPD, DIM, DIM, DIM, MLPD);

        // FC2: h += big @ fc2T^T + f2b
        bgemm<0, true, float, 2><<<dim3(6, 99), blk, 0, stream>>>(
            big, fc2T, fc2_b + (long)l * DIM, h,
            (int)M, DIM, MLPD, MLPD, MLPD, DIM);
    }

    // ---- final LN on cls rows -> lnout[0:32] (bf16) ----
    ln_kernel<<<dim3(8), blk, 0, stream>>>(
        h, (long)NSEQ * DIM, lnout, DIM, normf_w, normf_b, BV);

    // ---- head ----
    wconv_kernel<<<dim3(32, 24), blk, 0, stream>>>(head_w, qkvT, DIM, NCLS);
    bgemm<0, false, float, 2><<<dim3(8, 1), blk, 0, stream>>>(
        lnout, qkvT, head_b, out, BV, NCLS, DIM, DIM, DIM, NCLS);
}

// Round 4
// 3109.014 us; speedup vs baseline: 1.0425x; 1.0008x over previous
//
#include <hip/hip_runtime.h>
#include <hip/hip_bf16.h>
#include <type_traits>

// ViT-Base/16 forward. Round 7: attn rebuild — K staged via global_load_lds
// with slot-XOR swizzle (source-side, rule #21), Vt/P stride 232 (kills the
// 8-way PV bank conflict), V-loads-first T14 ordering. bgemm unchanged (R6).

#define BV   32
#define DIM  768
#define NHD  12
#define DH   64
#define NSEQ 197
#define NPAT 196
#define MLPD 3072
#define NCLS 1000
#define NLAYER 12

typedef __hip_bfloat16 bf16;
typedef __attribute__((ext_vector_type(8))) short s8v;    // 8 bf16 (4 VGPRs)
typedef __attribute__((ext_vector_type(4))) float f32x4;  // MFMA acc

#define GLDS16(gp, lp) __builtin_amdgcn_global_load_lds( \
    (const __attribute__((address_space(1))) void*)(gp), \
    (__attribute__((address_space(3))) void*)(lp), 16, 0, 0)

__device__ __forceinline__ short f2bf(float v) {
    return (short)__bfloat16_as_ushort(__float2bfloat16(v));
}

// ------------------------------------------------------------- MFMA GEMM ----
// C[M,N] = epilogue(A @ B^T + bias), A: [M,K] bf16 (lda), B: [N,K] bf16 (ldb),
// both K-contiguous. TO = float or bf16. ACT=1 -> exact GELU. RESID (float
// only): C += result. K % 32 == 0. Tile (MI*32)x128, BK=32, 4 waves (2x2).
// MI=4: 128x128 (48 KB). MI=2: 64x128 (36 KB) for grid-starved N=768 shapes.
// K-loop: 3-deep LDS pipeline (counted vmcnt) + XOR-swizzled tiles.
template<int ACT, bool RESID, typename TO, int MI>
__global__ __launch_bounds__(256)
void bgemm(const bf16* __restrict__ A, const bf16* __restrict__ B,
           const float* __restrict__ bias, TO* __restrict__ C,
           int M, int N, int K, int lda, int ldb, int ldc)
{
    constexpr int BM    = MI * 32;          // rows per block tile
    constexpr int ASIZE = MI * 1024;        // shorts per A tile
    constexpr int BUFS  = ASIZE + 4096;     // shorts per (A|B) buffer
    __shared__ short As[3 * BUFS];

    // XCD-aware swizzle: balanced bijection, XCD x owns a contiguous range.
    int nbx = gridDim.x;
    int nb  = nbx * gridDim.y;
    int bid = blockIdx.y * nbx + blockIdx.x;
    {
        int per = nb >> 3, rem = nb & 7;
        int x = bid & 7, loc = bid >> 3;
        bid = x * per + (x < rem ? x : rem) + loc;
    }
    const int m0 = (bid / nbx) * BM;
    const int n0 = (bid % nbx) * 128;

    const int tid  = threadIdx.x;
    const int wave = tid >> 6;
    const int lane = tid & 63;

    const int c0 = wave * 2, c1 = c0 + 1;
    const int rsub = lane >> 2;
    // T2: pre-swizzled source column (involution)
    const int kp8  = (((lane & 3) ^ ((rsub >> 1) & 3)) * 8);

    // A-chunk rows: MI=4 -> wave stages chunks c0,c1; MI=2 -> chunk `wave`.
    int ra0, ra1;
    if constexpr (MI == 4) { ra0 = m0 + c0 * 16 + rsub; ra1 = m0 + c1 * 16 + rsub; }
    else                   { ra0 = m0 + wave * 16 + rsub; ra1 = ra0; }
    if (ra0 > M - 1) ra0 = M - 1;
    if (ra1 > M - 1) ra1 = M - 1;
    int rb0 = n0 + c0 * 16 + rsub; if (rb0 > N - 1) rb0 = N - 1;
    int rb1 = n0 + c1 * 16 + rsub; if (rb1 > N - 1) rb1 = N - 1;

    const bf16* pa0 = A + (long)ra0 * lda + kp8;
    const bf16* pa1 = A + (long)ra1 * lda + kp8;
    const bf16* pb0 = B + (long)rb0 * ldb + kp8;
    const bf16* pb1 = B + (long)rb1 * ldb + kp8;

    const int wm = wave >> 1, wn = wave & 1;
    const int colr = lane & 15;
    const int quad = lane >> 4;

    f32x4 acc[MI][4];
    #pragma unroll
    for (int i = 0; i < MI; ++i)
        #pragma unroll
        for (int j = 0; j < 4; ++j)
            acc[i][j] = (f32x4){0.f, 0.f, 0.f, 0.f};

    // T2: swizzled fragment-read slot
    const int sq = quad ^ ((colr >> 1) & 3);
    const short* AsP = &As[(wm * (MI * 16) + colr) * 32 + sq * 8];
    const short* BsP = &As[ASIZE + (wn * 64 + colr) * 32 + sq * 8];

    auto STAGE = [&](int bufi) {
        int _o = bufi * BUFS;
        if constexpr (MI == 4) {
            GLDS16(pa0, &As[_o + c0 * 512]);
            GLDS16(pa1, &As[_o + c1 * 512]);
            pa1 += 32;
        } else {
            GLDS16(pa0, &As[_o + wave * 512]);
        }
        GLDS16(pb0, &As[_o + ASIZE + c0 * 512]);
        GLDS16(pb1, &As[_o + ASIZE + c1 * 512]);
        pa0 += 32; pb0 += 32; pb1 += 32;
    };

    const int nt = K >> 5;        // K / 32
    STAGE(0);
    STAGE(1);
    int cur = 0, nxt = 2;

    for (int t = 0; t < nt; ++t) {
        if (t + 2 < nt) {
            STAGE(nxt);
            nxt = (nxt == 2) ? 0 : nxt + 1;
            // 2 newer stages stay in flight; tile t's loads are done.
            if constexpr (MI == 4) asm volatile("s_waitcnt vmcnt(8)" ::: "memory");
            else                   asm volatile("s_waitcnt vmcnt(6)" ::: "memory");
        } else if (t + 1 < nt) {
            if constexpr (MI == 4) asm volatile("s_waitcnt vmcnt(4)" ::: "memory");
            else                   asm volatile("s_waitcnt vmcnt(3)" ::: "memory");
        } else {
            asm volatile("s_waitcnt vmcnt(0)" ::: "memory");
        }
        __builtin_amdgcn_s_barrier();            // tile t visible to all waves
        asm volatile("" ::: "memory");

        const short* Ab = AsP + cur * BUFS;
        const short* Bb = BsP + cur * BUFS;
        s8v a[MI], b[4];
        #pragma unroll
        for (int i = 0; i < MI; ++i) a[i] = *(const s8v*)(Ab + i * 512);
        #pragma unroll
        for (int j = 0; j < 4; ++j) b[j] = *(const s8v*)(Bb + j * 512);
        #pragma unroll
        for (int i = 0; i < MI; ++i)
            #pragma unroll
            for (int j = 0; j < 4; ++j)
                acc[i][j] = __builtin_amdgcn_mfma_f32_16x16x32_bf16(
                    a[i], b[j], acc[i][j], 0, 0, 0);

        cur = (cur == 2) ? 0 : cur + 1;
        asm volatile("" ::: "memory");
        __builtin_amdgcn_s_barrier();            // buf[cur] free to overwrite
        asm volatile("" ::: "memory");
    }

    // ---- epilogue: per-wave LDS transpose -> vectorized stores ----
    // C/D layout: col = lane&15, row = quad*4 + reg   [m89-verified]
    float* ep = ((float*)As) + wave * 1024;   // 16x64 fp32 per wave
    const int lrow = lane >> 2;
    const int lc4  = (lane & 3) * 16;

    #pragma unroll
    for (int i = 0; i < MI; ++i) {
        #pragma unroll
        for (int j = 0; j < 4; ++j)
            #pragma unroll
            for (int r = 0; r < 4; ++r)
                ep[(quad * 4 + r) * 64 + j * 16 + colr] = acc[i][j][r];
        __syncthreads();

        int gm = m0 + wm * (MI * 16) + i * 16 + lrow;
        int gn = n0 + wn * 64 + lc4;
        if (gm < M) {
            float vals[16];
            #pragma unroll
            for (int c = 0; c < 16; ++c) vals[c] = ep[lrow * 64 + lc4 + c];

            if (gn + 16 <= N) {
                if (bias) {
                    #pragma unroll
                    for (int c = 0; c < 16; ++c) vals[c] += bias[gn + c];
                }
                if (ACT == 1) {
                    #pragma unroll
                    for (int c = 0; c < 16; ++c)
                        vals[c] = 0.5f * vals[c] *
                                  (1.0f + erff(vals[c] * 0.70710678118654752f));
                }
                if constexpr (std::is_same<TO, float>::value) {
                    float* Cp = (float*)C + (long)gm * ldc + gn;
                    if constexpr (RESID) {
                        #pragma unroll
                        for (int c4 = 0; c4 < 4; ++c4) {
                            f32x4 old = *(const f32x4*)&Cp[c4 * 4];
                            #pragma unroll
                            for (int e = 0; e < 4; ++e) vals[c4 * 4 + e] += old[e];
                        }
                    }
                    #pragma unroll
                    for (int c4 = 0; c4 < 4; ++c4) {
                        f32x4 v;
                        #pragma unroll
                        for (int e = 0; e < 4; ++e) v[e] = vals[c4 * 4 + e];
                        *(f32x4*)&Cp[c4 * 4] = v;
                    }
                } else {
                    short* Cp = (short*)C + (long)gm * ldc + gn;
                    s8v v0, v1;
                    #pragma unroll
                    for (int e = 0; e < 8; ++e) { v0[e] = f2bf(vals[e]); v1[e] = f2bf(vals[8 + e]); }
                    *(s8v*)&Cp[0] = v0;
                    *(s8v*)&Cp[8] = v1;
                }
            } else {
                // partial-N fallback (head GEMM, N=1000)
                #pragma unroll
                for (int c = 0; c < 16; ++c) {
                    int g = gn + c;
                    if (g >= N) continue;
                    float v = vals[c];
                    if (bias) v += bias[g];
                    if (ACT == 1) v = 0.5f * v * (1.0f + erff(v * 0.70710678118654752f));
                    long idx = (long)gm * ldc + g;
                    if constexpr (RESID) v += ((const float*)C)[idx];
                    if constexpr (std::is_same<TO, float>::value) C[idx] = v;
                    else C[idx] = __float2bfloat16(v);
                }
            }
        }
        __syncthreads();
    }
}

// --------------------------------------------------- fused flash attention --
// One WG (4 waves) per (b, h, 64-row Q tile). qkv: [B*197][2304] bf16
// (q|k|v, head-contig 64). O: [B*197][768] bf16.
// K: LDS [224 rows][8 slots x 16B], slot s of row r at physical s^(r&7)
//    (staged by global_load_lds with pre-swizzled source column).
// P overlays K region after S-phase: [64][stride 232] bf16.
// Vt: [64 d][stride 232] bf16 (d-major); stride 232 -> conflict-free b128.
__global__ __launch_bounds__(256)
void attn_kernel(const bf16* __restrict__ qkv, bf16* __restrict__ O)
{
    __shared__ short Ks[14848];      // 29,696 B: union of K (28,672) / P (29,696)
    __shared__ short Vt[14848];      // 64 x 232-stride (224 cols used)

    const int tid  = threadIdx.x;
    const int wave = tid >> 6;
    const int lane = tid & 63;
    const int q0 = blockIdx.x * 64;
    const int b  = blockIdx.y / NHD;
    const int h  = blockIdx.y % NHD;
    const bf16* base = qkv + (long)b * NSEQ * (3 * DIM);

    const int colr = lane & 15;
    const int quad = lane >> 4;

    // ---- Q fragments straight to registers ----
    int qr = q0 + wave * 16 + colr; if (qr > NSEQ - 1) qr = NSEQ - 1;
    const bf16* qp = &base[(long)qr * (3 * DIM) + h * DH + quad * 8];
    s8v qa0 = *(const s8v*)qp;
    s8v qa1 = *(const s8v*)(qp + 32);

    // ---- V to regs first (T14: latency hides under K-GLDS + Vt writes) ----
    const int seqL = tid & 31, dc = tid >> 5;   // dc 0..7
    s8v vreg[7];
    #pragma unroll
    for (int st = 0; st < 7; ++st) {
        int gr = st * 32 + seqL; if (gr > NSEQ - 1) gr = NSEQ - 1;
        vreg[st] = *(const s8v*)&base[(long)gr * (3 * DIM) + 2 * DIM + h * DH + dc * 8];
    }

    // ---- K -> LDS via global_load_lds, source-side slot swizzle ----
    {
        int r8   = lane >> 3;                    // row within 8-row chunk
        int scol = ((lane & 7) ^ r8) * 8;        // swizzled source col (shorts)
        #pragma unroll
        for (int p = 0; p < 7; ++p) {
            int chunk = wave * 7 + p;            // 0..27 (rows chunk*8..+7)
            int gr = chunk * 8 + r8; if (gr > NSEQ - 1) gr = NSEQ - 1;
            GLDS16(&base[(long)gr * (3 * DIM) + DIM + h * DH + scol],
                   &Ks[chunk * 512]);            // 512 shorts = 1 KB/chunk
        }
    }

    // ---- Vt writes (compiler waits on vreg only; K-GLDS stays in flight) ----
    #pragma unroll
    for (int st = 0; st < 7; ++st) {
        int seq = st * 32 + seqL;
        #pragma unroll
        for (int i = 0; i < 8; ++i)
            Vt[(dc * 8 + i) * 232 + seq] = vreg[st][i];
    }
    __syncthreads();   // drains vmcnt(0) (K-GLDS) + lgkmcnt, then barrier

    // ---- S = Q @ K^T : each wave = 16 rows x 224 cols, K=64 ----
    // b-frag row j*16+colr, logical slot quad+4*kk -> physical ^ (colr&7)
    f32x4 s[14];
    #pragma unroll
    for (int j = 0; j < 14; ++j) s[j] = (f32x4){0.f, 0.f, 0.f, 0.f};
    #pragma unroll
    for (int j = 0; j < 14; ++j) {
        int rb = (j * 16 + colr) * 64;
        s8v bf0 = *(const s8v*)&Ks[rb + ((quad ^ (colr & 7)) * 8)];
        s[j] = __builtin_amdgcn_mfma_f32_16x16x32_bf16(qa0, bf0, s[j], 0, 0, 0);
        s8v bf1 = *(const s8v*)&Ks[rb + (((quad + 4) ^ (colr & 7)) * 8)];
        s[j] = __builtin_amdgcn_mfma_f32_16x16x32_bf16(qa1, bf1, s[j], 0, 0, 0);
    }

    // ---- softmax (rows: quad*4+r within wave slice; col: j*16+colr) ----
    float mx[4] = {-1e30f, -1e30f, -1e30f, -1e30f};
    #pragma unroll
    for (int j = 0; j < 14; ++j) {
        int c = j * 16 + colr;
        #pragma unroll
        for (int r = 0; r < 4; ++r) {
            s[j][r] *= 0.125f;
            if (c < NSEQ) mx[r] = fmaxf(mx[r], s[j][r]);
        }
    }
    #pragma unroll
    for (int off = 1; off <= 8; off <<= 1)
        #pragma unroll
        for (int r = 0; r < 4; ++r)
            mx[r] = fmaxf(mx[r], __shfl_xor(mx[r], off));

    float sum[4] = {0.f, 0.f, 0.f, 0.f};
    #pragma unroll
    for (int j = 0; j < 14; ++j) {
        int c = j * 16 + colr;
        #pragma unroll
        for (int r = 0; r < 4; ++r) {
            float v = (c < NSEQ) ? expf(s[j][r] - mx[r]) : 0.f;
            s[j][r] = v;
            sum[r] += v;
        }
    }
    #pragma unroll
    for (int off = 1; off <= 8; off <<= 1)
        #pragma unroll
        for (int r = 0; r < 4; ++r)
            sum[r] += __shfl_xor(sum[r], off);
    float inv[4];
    #pragma unroll
    for (int r = 0; r < 4; ++r) inv[r] = 1.0f / sum[r];

    __syncthreads();                 // all waves done reading Ks
    short* P = Ks;                   // overlay: [64 rows][stride 232] bf16
    #pragma unroll
    for (int j = 0; j < 14; ++j)
        #pragma unroll
        for (int r = 0; r < 4; ++r)
            P[(wave * 16 + quad * 4 + r) * 232 + j * 16 + colr] =
                f2bf(s[j][r] * inv[r]);

    __syncthreads();

    // ---- O = P @ V : per wave 16 rows x 64 dims, K=224 ----
    f32x4 o[4];
    #pragma unroll
    for (int j2 = 0; j2 < 4; ++j2) o[j2] = (f32x4){0.f, 0.f, 0.f, 0.f};
    #pragma unroll
    for (int ks = 0; ks < 7; ++ks) {
        s8v a = *(const s8v*)&P[(wave * 16 + colr) * 232 + quad * 8 + ks * 32];
        #pragma unroll
        for (int j2 = 0; j2 < 4; ++j2) {
            s8v bf = *(const s8v*)&Vt[(j2 * 16 + colr) * 232 + quad * 8 + ks * 32];
            o[j2] = __builtin_amdgcn_mfma_f32_16x16x32_bf16(a, bf, o[j2], 0, 0, 0);
        }
    }

    #pragma unroll
    for (int j2 = 0; j2 < 4; ++j2)
        #pragma unroll
        for (int r = 0; r < 4; ++r) {
            int qrow = q0 + wave * 16 + quad * 4 + r;
            if (qrow < NSEQ)
                O[((long)b * NSEQ + qrow) * DIM + h * DH + j2 * 16 + colr] =
                    __float2bfloat16(o[j2][r]);
        }
}

// ------------------------------------------------- weight transpose->bf16 ---
__device__ __forceinline__ void wconv_tile(const float* __restrict__ in,
                                           bf16* __restrict__ out,
                                           int R, int C, int bx, int by)
{
    __shared__ float t[32][33];
    int c0 = bx * 32, r0 = by * 32;
    int tx = threadIdx.x & 31, ty = threadIdx.x >> 5;
    #pragma unroll
    for (int i = 0; i < 4; ++i) {
        int r = r0 + ty + 8 * i;
        if (r < R && c0 + tx < C) t[ty + 8 * i][tx] = in[(long)r * C + c0 + tx];
    }
    __syncthreads();
    #pragma unroll
    for (int i = 0; i < 4; ++i) {
        int c = c0 + ty + 8 * i;
        int r = r0 + tx;
        if (c < C && r < R) out[(long)c * R + r] = __float2bfloat16(t[tx][ty + 8 * i]);
    }
}

__global__ __launch_bounds__(256)
void wconv_kernel(const float* __restrict__ in, bf16* __restrict__ out,
                  int R, int C)
{
    wconv_tile(in, out, R, C, blockIdx.x, blockIdx.y);
}

// All four per-layer weight transposes in one launch (segmented grid).
__global__ __launch_bounds__(256)
void wconv4_kernel(const float* __restrict__ qw, const float* __restrict__ pw,
                   const float* __restrict__ f1w, const float* __restrict__ f2w,
                   bf16* __restrict__ qT, bf16* __restrict__ pT,
                   bf16* __restrict__ f1T, bf16* __restrict__ f2T)
{
    int bid = blockIdx.x;
    if (bid < 1728)      { int t = bid;        wconv_tile(qw,  qT,  768,  2304, t % 72, t / 72); }
    else if (bid < 2304) { int t = bid - 1728; wconv_tile(pw,  pT,  768,  768,  t % 24, t / 24); }
    else if (bid < 4608) { int t = bid - 2304; wconv_tile(f1w, f1T, 768,  3072, t % 96, t / 96); }
    else                 { int t = bid - 4608; wconv_tile(f2w, f2T, 3072, 768,  t % 24, t / 24); }
}

// ---------------------------------------------------------------- LayerNorm -
// One wave per row (DIM=768 = 64 lanes x 12), 4 rows per block. No LDS/barrier.
__global__ __launch_bounds__(256)
void ln_kernel(const float* __restrict__ in, long in_stride,
               bf16* __restrict__ out, long out_stride,
               const float* __restrict__ w, const float* __restrict__ b,
               int nrows)
{
    int wave = threadIdx.x >> 6, lane = threadIdx.x & 63;
    long r = (long)blockIdx.x * 4 + wave;
    if (r >= nrows) return;
    const float* x = in + r * in_stride;
    bf16* y = out + r * out_stride;

    f32x4 c[3];
    float s = 0.f, s2 = 0.f;
    #pragma unroll
    for (int p = 0; p < 3; ++p) {
        c[p] = *(const f32x4*)&x[p * 256 + lane * 4];
        #pragma unroll
        for (int e = 0; e < 4; ++e) { s += c[p][e]; s2 += c[p][e] * c[p][e]; }
    }
    #pragma unroll
    for (int off = 1; off <= 32; off <<= 1) {
        s  += __shfl_xor(s, off);
        s2 += __shfl_xor(s2, off);
    }
    float mean = s * (1.0f / (float)DIM);
    float var  = s2 * (1.0f / (float)DIM) - mean * mean;
    float rstd = 1.0f / sqrtf(var + 1e-6f);

    #pragma unroll
    for (int p = 0; p < 3; ++p) {
        f32x4 wv = *(const f32x4*)&w[p * 256 + lane * 4];
        f32x4 bv = *(const f32x4*)&b[p * 256 + lane * 4];
        #pragma unroll
        for (int e = 0; e < 4; ++e)
            y[p * 256 + lane * 4 + e] =
                __float2bfloat16((c[p][e] - mean) * rstd * wv[e] + bv[e]);
    }
}

// ---------------------------------------------------------------- im2col ----
__global__ __launch_bounds__(256)
void im2col_kernel(const float* __restrict__ x, bf16* __restrict__ out)
{
    long i = (long)blockIdx.x * 256 + threadIdx.x;
    const long total = (long)BV * NPAT * DIM;
    if (i >= total) return;
    int col = (int)(i % DIM);
    long row = i / DIM;
    int c  = col >> 8;
    int py = (col >> 4) & 15;
    int px = col & 15;
    int b  = (int)(row / NPAT);
    int pp = (int)(row % NPAT);
    int gy = pp / 14, gx = pp % 14;
    out[i] = __float2bfloat16(
        x[(((long)(b * 3 + c) * 224 + gy * 16 + py) * 224) + gx * 16 + px]);
}

// ---------------------------------------------------------------- assemble --
__global__ __launch_bounds__(256)
void assemble_kernel(const float* __restrict__ tmp, const float* __restrict__ cls,
                     const float* __restrict__ pos, float* __restrict__ h)
{
    long i = (long)blockIdx.x * 256 + threadIdx.x;
    const long total = (long)BV * NSEQ * DIM;
    if (i >= total) return;
    int d = (int)(i % DIM);
    long row = i / DIM;
    int n = (int)(row % NSEQ);
    long b = row / NSEQ;
    float v;
    if (n == 0) v = cls[d];
    else        v = tmp[(b * NPAT + (n - 1)) * DIM + d];
    h[i] = v + pos[(long)n * DIM + d];
}

// ---------------------------------------------------------------- launch ----
extern "C" void kernel_launch(void* const* d_in, const int* in_sizes, int n_in,
                              void* d_out, int out_size, void* d_ws, size_t ws_size,
                              hipStream_t stream)
{
    const float* x        = (const float*)d_in[0];
    const float* patch_w  = (const float*)d_in[1];
    const float* patch_b  = (const float*)d_in[2];
    const float* cls_tok  = (const float*)d_in[3];
    const float* pos_emb  = (const float*)d_in[4];
    const float* ln1_w    = (const float*)d_in[5];
    const float* ln1_b    = (const float*)d_in[6];
    const float* qkv_w    = (const float*)d_in[7];
    const float* qkv_b    = (const float*)d_in[8];
    const float* proj_w   = (const float*)d_in[9];
    const float* proj_b   = (const float*)d_in[10];
    const float* ln2_w    = (const float*)d_in[11];
    const float* ln2_b    = (const float*)d_in[12];
    const float* fc1_w    = (const float*)d_in[13];
    const float* fc1_b    = (const float*)d_in[14];
    const float* fc2_w    = (const float*)d_in[15];
    const float* fc2_b    = (const float*)d_in[16];
    const float* normf_w  = (const float*)d_in[17];
    const float* normf_b  = (const float*)d_in[18];
    const float* head_w   = (const float*)d_in[19];
    const float* head_b   = (const float*)d_in[20];
    float* out = (float*)d_out;

    const long M = (long)BV * NSEQ;   // 6304
    const long MP = (long)BV * NPAT;  // 6272

    // ---- workspace layout ----
    float* h      = (float*)d_ws;                 // [6304][768] fp32
    float* ptmp   = h + 4841472L;                 // patch-embed tmp fp32 [6272][768]
    bf16*  qkv    = (bf16*)(ptmp + 4816896L);     // [6304][2304] bf16
    bf16*  lnout  = qkv + 14524416L;              // [6304][768] bf16 (ln out / O)
    bf16*  big    = lnout + 4841472L;             // [6304][3072] bf16 (patches/mlp)
    bf16*  wT     = big + 19365888L;              // per-layer transposed weights
    bf16*  qkvT = wT;                             // [2304][768]
    bf16*  projT = wT + 1769472L;                 // [768][768]
    bf16*  fc1T  = wT + 2359296L;                 // [3072][768]
    bf16*  fc2T  = wT + 4718592L;                 // [768][3072]

    dim3 blk(256);

    // ---- patch embed ----
    wconv_kernel<<<dim3(24, 24), blk, 0, stream>>>(patch_w, qkvT, DIM, DIM);
    im2col_kernel<<<dim3((unsigned)((MP * DIM + 255) / 256)), blk, 0, stream>>>(x, big);
    bgemm<0, false, float, 2><<<dim3(6, 98), blk, 0, stream>>>(
        big, qkvT, patch_b, ptmp, (int)MP, DIM, DIM, DIM, DIM, DIM);
    assemble_kernel<<<dim3((unsigned)((M * DIM + 255) / 256)), blk, 0, stream>>>(
        ptmp, cls_tok, pos_emb, h);

    // ---- transformer blocks ----
    for (int l = 0; l < NLAYER; ++l) {
        wconv4_kernel<<<dim3(6912), blk, 0, stream>>>(
            qkv_w + (long)l * DIM * 3 * DIM, proj_w + (long)l * DIM * DIM,
            fc1_w + (long)l * DIM * MLPD,    fc2_w + (long)l * MLPD * DIM,
            qkvT, projT, fc1T, fc2T);

        // LN1: h -> lnout (bf16)
        ln_kernel<<<dim3((unsigned)((M + 3) / 4)), blk, 0, stream>>>(
            h, DIM, lnout, DIM, ln1_w + (long)l * DIM, ln1_b + (long)l * DIM, (int)M);

        // QKV: lnout @ qkvT^T + qb -> qkv (bf16)
        bgemm<0, false, bf16, 4><<<dim3(18, 50), blk, 0, stream>>>(
            lnout, qkvT, qkv_b + (long)l * 3 * DIM, qkv,
            (int)M, 3 * DIM, DIM, DIM, DIM, 3 * DIM);

        // fused attention -> lnout (bf16 O)
        attn_kernel<<<dim3(4, BV * NHD), blk, 0, stream>>>(qkv, lnout);

        // proj: h += O @ projT^T + pb
        bgemm<0, true, float, 2><<<dim3(6, 99), blk, 0, stream>>>(
            lnout, projT, proj_b + (long)l * DIM, h,
            (int)M, DIM, DIM, DIM, DIM, DIM);

        // LN2: h -> lnout (bf16)
        ln_kernel<<<dim3((unsigned)((M + 3) / 4)), blk, 0, stream>>>(
            h, DIM, lnout, DIM, ln2_w + (long)l * DIM, ln2_b + (long)l * DIM, (int)M);

        // FC1 + GELU -> big (bf16)
        bgemm<1, false, bf16, 4><<<dim3(24, 50), blk, 0, stream>>>(
            lnout, fc1T, fc1_b + (long)l * MLPD, big,
            (int)M, MLPD, DIM, DIM, DIM, MLPD);

        // FC2: h += big @ fc2T^T + f2b
        bgemm<0, true, float, 2><<<dim3(6, 99), blk, 0, stream>>>(
            big, fc2T, fc2_b + (long)l * DIM, h,
            (int)M, DIM, MLPD, MLPD, MLPD, DIM);
    }

    // ---- final LN on cls rows -> lnout[0:32] (bf16) ----
    ln_kernel<<<dim3(8), blk, 0, stream>>>(
        h, (long)NSEQ * DIM, lnout, DIM, normf_w, normf_b, BV);

    // ---- head ----
    wconv_kernel<<<dim3(32, 24), blk, 0, stream>>>(head_w, qkvT, DIM, NCLS);
    bgemm<0, false, float, 2><<<dim3(8, 1), blk, 0, stream>>>(
        lnout, qkvT, head_b, out, BV, NCLS, DIM, DIM, DIM, NCLS);
}